// Round 6
// baseline (78644.098 us; speedup 1.0000x reference)
//
#include <hip/hip_runtime.h>
#include <stdint.h>

// Problem constants (match reference)
#define T_STEPS 1024
#define BATCH   64
#define NDIM    512
#define BN      (BATCH * NDIM)   // 32768
#define ALPHA   0.1f

// ---------------------------------------------------------------------------
// Helpers: bf16 pack/unpack (RNE). Only W is stored bf16; r and accumulation
// stay fp32. Measured absmax 0.0078 vs threshold 0.0311 (round 5).
// ---------------------------------------------------------------------------
__device__ __forceinline__ unsigned short f2bf(float f) {
    unsigned int u = __float_as_uint(f);
    unsigned int r = (u + 0x7fffu + ((u >> 16) & 1u)) >> 16;  // round-nearest-even
    return (unsigned short)r;
}
__device__ __forceinline__ float bflo(unsigned int d) { return __uint_as_float(d << 16); }
__device__ __forceinline__ float bfhi(unsigned int d) { return __uint_as_float(d & 0xffff0000u); }

// ---------------------------------------------------------------------------
// Prep: masked, transposed, bf16-packed weights in workspace.
// Wp[k8 * 512 + n] = uint4 holding W_eff[n][8*k8 .. 8*k8+7] as 8 bf16.
// ---------------------------------------------------------------------------
__global__ void rnn_prep_kernel(const float* __restrict__ W_rec,
                                const int* __restrict__ rec_mask,
                                uint4* __restrict__ Wp) {
    const int k8 = blockIdx.x;    // 0..63
    const int n  = threadIdx.x;   // 0..511
    const int base = n * NDIM + k8 * 8;
    unsigned int words[4];
#pragma unroll
    for (int p = 0; p < 4; ++p) {
        float w0 = W_rec[base + 2 * p];
        float w1 = W_rec[base + 2 * p + 1];
        int   m0 = rec_mask[base + 2 * p];
        int   m1 = rec_mask[base + 2 * p + 1];
        unsigned int lo = m0 ? (unsigned int)f2bf(w0) : 0u;
        unsigned int hi = m1 ? (unsigned int)f2bf(w1) : 0u;
        words[p] = lo | (hi << 16);
    }
    uint4 o;
    o.x = words[0]; o.y = words[1]; o.z = words[2]; o.w = words[3];
    Wp[(k8 << 9) | n] = o;
}

// ---------------------------------------------------------------------------
// Scan with explicit 4-buffer, 2-chunk-ahead register pipeline.
// Round-5 diagnosis: VGPR=24 / VALUBusy=7% -> compiler rolled the W loop,
// ~1 outstanding L2 load, 27K cyc/step vs 2K VALU floor. Fix: named register
// arrays wA..wD (compile-time indices only), 16 loads in flight. W addresses
// repeat every step, and 8 chunks % 4 buffers == 0, so the rotation carries
// across the step boundary: chunks 0,1 of step t+1 prefetch during chunks
// 6,7 of step t, hiding the barrier/tanh gap as well.
// ---------------------------------------------------------------------------
#define PREF(BUF, CH) do {                                              \
    _Pragma("unroll")                                                   \
    for (int j = 0; j < 8; ++j) {                                       \
        BUF[j] = wp[((CH) * 8 + j) << 9];                               \
    }                                                                   \
} while (0)

#define COMPUTE(BUF, CH) do {                                           \
    _Pragma("unroll")                                                   \
    for (int j = 0; j < 8; ++j) {                                       \
        const uint4 w = BUF[j];                                         \
        const int k8c = (CH) * 8 + j;                                   \
        const float4 ra = *reinterpret_cast<const float4*>(&rr[k8c * 8]);     \
        const float4 rb = *reinterpret_cast<const float4*>(&rr[k8c * 8 + 4]); \
        a0 = fmaf(bflo(w.x), ra.x, a0);                                 \
        a1 = fmaf(bfhi(w.x), ra.y, a1);                                 \
        a2 = fmaf(bflo(w.y), ra.z, a2);                                 \
        a3 = fmaf(bfhi(w.y), ra.w, a3);                                 \
        a4 = fmaf(bflo(w.z), rb.x, a4);                                 \
        a5 = fmaf(bfhi(w.z), rb.y, a5);                                 \
        a6 = fmaf(bflo(w.w), rb.z, a6);                                 \
        a7 = fmaf(bfhi(w.w), rb.w, a7);                                 \
    }                                                                   \
} while (0)

__global__ __launch_bounds__(512, 2)
void rnn_scan_kernel(const float* __restrict__ inputs,
                     const float* __restrict__ bias,
                     const float* __restrict__ init_x,
                     const uint4* __restrict__ Wp,
                     float* __restrict__ out) {
    const int b = blockIdx.x;     // 0..63
    const int n = threadIdx.x;    // 0..511

    __shared__ float rs[2][NDIM];

    const float bias_n = bias[n];
    float x = init_x[n];

    // t = 0 output block: broadcast initial state
    out[(size_t)b * NDIM + n] = x;

    const float* u_ptr = inputs + (size_t)b * NDIM + n;
    float*       o_ptr = out + (size_t)BN + (size_t)b * NDIM + n;
    const uint4* wp = Wp + n;     // per-lane base; chunk offsets are wave-uniform

    uint4 wA[8], wB[8], wC[8], wD[8];
    PREF(wA, 0);                  // prologue: chunks 0,1 in flight
    PREF(wB, 1);

    for (int t = 0; t < T_STEPS; ++t) {
        const int buf = t & 1;
        const float u = __builtin_nontemporal_load(u_ptr);  // issue early
        rs[buf][n] = tanhf(x);
        __syncthreads();
        const float* rr = rs[buf];

        float a0 = 0.f, a1 = 0.f, a2 = 0.f, a3 = 0.f;
        float a4 = 0.f, a5 = 0.f, a6 = 0.f, a7 = 0.f;

#pragma unroll
        for (int c = 0; c < 8; ++c) {
            const int pc = (c + 2) & 7;   // chunk to prefetch (wraps to next step)
            const int pb = (c + 2) & 3;   // buffer receiving it
            if      (pb == 0) PREF(wA, pc);
            else if (pb == 1) PREF(wB, pc);
            else if (pb == 2) PREF(wC, pc);
            else              PREF(wD, pc);
            const int cb = c & 3;         // buffer holding chunk c
            if      (cb == 0) COMPUTE(wA, c);
            else if (cb == 1) COMPUTE(wB, c);
            else if (cb == 2) COMPUTE(wC, c);
            else              COMPUTE(wD, c);
        }

        const float acc = ((a0 + a1) + (a2 + a3)) + ((a4 + a5) + (a6 + a7));
        // x_new = x + alpha * (-x + acc + u + bias)
        x = fmaf(ALPHA, (acc + u + bias_n) - x, x);
        __builtin_nontemporal_store(x, o_ptr);  // don't let writes evict W in L2

        u_ptr += BN;
        o_ptr += BN;
        // One barrier per step: next iteration writes the other LDS buffer;
        // a thread can only reach the write of buffer B at t+2 after passing
        // the barrier at t+1, which all threads reach only after finishing
        // their t-compute reads of buffer B.
    }
}

// ---------------------------------------------------------------------------
// Launch
// ---------------------------------------------------------------------------
extern "C" void kernel_launch(void* const* d_in, const int* in_sizes, int n_in,
                              void* d_out, int out_size, void* d_ws, size_t ws_size,
                              hipStream_t stream) {
    const float* inputs   = (const float*)d_in[0];  // [T, B, N] fp32
    const float* W_rec    = (const float*)d_in[1];  // [N, N] fp32
    const int*   rec_mask = (const int*)d_in[2];    // [N, N] int (bool)
    const float* bias     = (const float*)d_in[3];  // [1, N] fp32
    const float* init_x   = (const float*)d_in[4];  // [N] fp32
    float*       out      = (float*)d_out;          // [T+1, B, N] fp32

    uint4* Wp = (uint4*)d_ws;  // 512 KB: masked W^T, bf16-packed

    rnn_prep_kernel<<<64, 512, 0, stream>>>(W_rec, rec_mask, Wp);
    rnn_scan_kernel<<<64, 512, 0, stream>>>(inputs, bias, init_x, Wp, out);
}

// Round 10
// 78528.210 us; speedup vs baseline: 1.0015x; 1.0015x over previous
//
#include <hip/hip_runtime.h>
#include <stdint.h>

// Problem constants (match reference)
#define T_STEPS 1024
#define BATCH   64
#define NDIM    512
#define BN      (BATCH * NDIM)   // 32768
#define ALPHA   0.1f

// ---------------------------------------------------------------------------
// Helpers: bf16 pack/unpack (RNE). Only W is stored bf16; r and accumulation
// stay fp32. Measured absmax 0.0078 vs threshold 0.0311 (rounds 5/6).
// ---------------------------------------------------------------------------
__device__ __forceinline__ unsigned short f2bf(float f) {
    unsigned int u = __float_as_uint(f);
    unsigned int r = (u + 0x7fffu + ((u >> 16) & 1u)) >> 16;  // round-nearest-even
    return (unsigned short)r;
}
__device__ __forceinline__ float bflo(unsigned int d) { return __uint_as_float(d << 16); }
__device__ __forceinline__ float bfhi(unsigned int d) { return __uint_as_float(d & 0xffff0000u); }

// ---------------------------------------------------------------------------
// Prep: masked, transposed, bf16-packed weights in workspace.
// Wp[k8 * 512 + n] = uint4 holding W_eff[n][8*k8 .. 8*k8+7] as 8 bf16.
// ---------------------------------------------------------------------------
__global__ void rnn_prep_kernel(const float* __restrict__ W_rec,
                                const int* __restrict__ rec_mask,
                                uint4* __restrict__ Wp) {
    const int k8 = blockIdx.x;    // 0..63
    const int n  = threadIdx.x;   // 0..511
    const int base = n * NDIM + k8 * 8;
    unsigned int words[4];
#pragma unroll
    for (int p = 0; p < 4; ++p) {
        float w0 = W_rec[base + 2 * p];
        float w1 = W_rec[base + 2 * p + 1];
        int   m0 = rec_mask[base + 2 * p];
        int   m1 = rec_mask[base + 2 * p + 1];
        unsigned int lo = m0 ? (unsigned int)f2bf(w0) : 0u;
        unsigned int hi = m1 ? (unsigned int)f2bf(w1) : 0u;
        words[p] = lo | (hi << 16);
    }
    uint4 o;
    o.x = words[0]; o.y = words[1]; o.z = words[2]; o.w = words[3];
    Wp[(k8 << 9) | n] = o;
}

// ---------------------------------------------------------------------------
// Scan, round-7 version: round-5 structure (proven L2-resident W, 11.7 ms,
// FETCH 67 MB) + MINIMAL latency fix. Round-5 diagnosis: VGPR=24, rolled
// loop, ~1 outstanding L2 load -> 64 serialized ~400cy waits/step. Round-6
// post-mortem: 4 buffers (128 buffer VGPRs) busted the register budget and
// L2 locality (FETCH 20 GB). This version: TWO buffers x 8 uint4 (64 VGPRs),
// 1 chunk ahead = 8 loads in flight; chunk compute (~600cy/CU) > L2 latency
// (~400cy) so waits collapse after chunk 0; the c==7 prefetch wraps to chunk
// 0 of the NEXT step (same addresses every step), covering the barrier gap.
// No nontemporal hints (candidate culprit in round 6 — removed).
// ---------------------------------------------------------------------------
#define PREF(BUF, CH) do {                                              \
    _Pragma("unroll")                                                   \
    for (int j = 0; j < 8; ++j) {                                       \
        BUF[j] = wp[((CH) * 8 + j) << 9];                               \
    }                                                                   \
} while (0)

#define COMPUTE(BUF, CH) do {                                           \
    _Pragma("unroll")                                                   \
    for (int j = 0; j < 8; ++j) {                                       \
        const uint4 w = BUF[j];                                         \
        const int k8c = (CH) * 8 + j;                                   \
        const float4 ra = *reinterpret_cast<const float4*>(&rr[k8c * 8]);     \
        const float4 rb = *reinterpret_cast<const float4*>(&rr[k8c * 8 + 4]); \
        a0 = fmaf(bflo(w.x), ra.x, a0);                                 \
        a1 = fmaf(bfhi(w.x), ra.y, a1);                                 \
        a2 = fmaf(bflo(w.y), ra.z, a2);                                 \
        a3 = fmaf(bfhi(w.y), ra.w, a3);                                 \
        a4 = fmaf(bflo(w.z), rb.x, a4);                                 \
        a5 = fmaf(bfhi(w.z), rb.y, a5);                                 \
        a6 = fmaf(bflo(w.w), rb.z, a6);                                 \
        a7 = fmaf(bfhi(w.w), rb.w, a7);                                 \
    }                                                                   \
} while (0)

__global__ __launch_bounds__(512, 1)
void rnn_scan_kernel(const float* __restrict__ inputs,
                     const float* __restrict__ bias,
                     const float* __restrict__ init_x,
                     const uint4* __restrict__ Wp,
                     float* __restrict__ out) {
    const int b = blockIdx.x;     // 0..63
    const int n = threadIdx.x;    // 0..511

    __shared__ float rs[2][NDIM];

    const float bias_n = bias[n];
    float x = init_x[n];

    // t = 0 output block: broadcast initial state
    out[(size_t)b * NDIM + n] = x;

    const float* u_ptr = inputs + (size_t)b * NDIM + n;
    float*       o_ptr = out + (size_t)BN + (size_t)b * NDIM + n;
    const uint4* wp = Wp + n;     // per-lane base; chunk offsets are uniform

    uint4 pA[8], pB[8];
    PREF(pA, 0);                  // prologue: chunk 0 in flight

    for (int t = 0; t < T_STEPS; ++t) {
        const float u = *u_ptr;   // issue before the barrier; used at step end
        const int buf = t & 1;
        rs[buf][n] = tanhf(x);
        __syncthreads();
        const float* rr = rs[buf];

        float a0 = 0.f, a1 = 0.f, a2 = 0.f, a3 = 0.f;
        float a4 = 0.f, a5 = 0.f, a6 = 0.f, a7 = 0.f;

#pragma unroll
        for (int c = 0; c < 8; ++c) {
            const int nc = (c + 1) & 7;      // chunk to prefetch (wraps to next step)
            if ((c & 1) == 0) { PREF(pB, nc); COMPUTE(pA, c); }
            else              { PREF(pA, nc); COMPUTE(pB, c); }
        }

        const float acc = ((a0 + a1) + (a2 + a3)) + ((a4 + a5) + (a6 + a7));
        // x_new = x + alpha * (-x + acc + u + bias)
        x = fmaf(ALPHA, (acc + u + bias_n) - x, x);
        *o_ptr = x;

        u_ptr += BN;
        o_ptr += BN;
        // One barrier per step: next iteration writes the other LDS buffer;
        // a thread can only reach the write of buffer B at t+2 after passing
        // the barrier at t+1, which all threads reach only after finishing
        // their t-compute reads of buffer B.
    }
}

// ---------------------------------------------------------------------------
// Launch
// ---------------------------------------------------------------------------
extern "C" void kernel_launch(void* const* d_in, const int* in_sizes, int n_in,
                              void* d_out, int out_size, void* d_ws, size_t ws_size,
                              hipStream_t stream) {
    const float* inputs   = (const float*)d_in[0];  // [T, B, N] fp32
    const float* W_rec    = (const float*)d_in[1];  // [N, N] fp32
    const int*   rec_mask = (const int*)d_in[2];    // [N, N] int (bool)
    const float* bias     = (const float*)d_in[3];  // [1, N] fp32
    const float* init_x   = (const float*)d_in[4];  // [N] fp32
    float*       out      = (float*)d_out;          // [T+1, B, N] fp32

    uint4* Wp = (uint4*)d_ws;  // 512 KB: masked W^T, bf16-packed

    rnn_prep_kernel<<<64, 512, 0, stream>>>(W_rec, rec_mask, Wp);
    rnn_scan_kernel<<<64, 512, 0, stream>>>(inputs, bias, init_x, Wp, out);
}

// Round 11
// 37530.212 us; speedup vs baseline: 2.0955x; 2.0924x over previous
//
#include <hip/hip_runtime.h>
#include <stdint.h>

// Problem constants (match reference)
#define T_STEPS 1024
#define BATCH   64
#define NDIM    512
#define BN      (BATCH * NDIM)   // 32768
#define ALPHA   0.1f

#define NSLICE  4                // column-slices per batch row
#define COLS    128              // columns per slice
#define QK      4                // k-quarters per column

// Workspace layout (bytes)
#define WP_BYTES    (64 * 512 * 16)            // 512 KB packed W
#define EXCH_OFF    WP_BYTES                   // f32 exch[64][4][2][COLS] = 256 KB
#define EXCH_FLOATS (BATCH * NSLICE * 2 * COLS)
#define FLAGS_OFF   (EXCH_OFF + EXCH_FLOATS * 4)  // int flags[64][4][2][32] = 64 KB

// ---------------------------------------------------------------------------
// bf16 pack/unpack (RNE). Only W is bf16; r/accum fp32. Measured absmax
// 0.0078 vs threshold 0.0311 (rounds 5/6/10).
// ---------------------------------------------------------------------------
__device__ __forceinline__ unsigned short f2bf(float f) {
    unsigned int u = __float_as_uint(f);
    unsigned int r = (u + 0x7fffu + ((u >> 16) & 1u)) >> 16;
    return (unsigned short)r;
}
__device__ __forceinline__ float bflo(unsigned int d) { return __uint_as_float(d << 16); }
__device__ __forceinline__ float bfhi(unsigned int d) { return __uint_as_float(d & 0xffff0000u); }

// ---------------------------------------------------------------------------
// Prep: masked, transposed, bf16-packed weights.
// Wp[k8 * 512 + n] = uint4 of W_eff[n][8*k8 .. 8*k8+7] as 8 bf16.
// ---------------------------------------------------------------------------
__global__ void rnn_prep_kernel(const float* __restrict__ W_rec,
                                const int* __restrict__ rec_mask,
                                uint4* __restrict__ Wp) {
    const int k8 = blockIdx.x;
    const int n  = threadIdx.x;
    const int base = n * NDIM + k8 * 8;
    unsigned int words[4];
#pragma unroll
    for (int p = 0; p < 4; ++p) {
        float w0 = W_rec[base + 2 * p];
        float w1 = W_rec[base + 2 * p + 1];
        int   m0 = rec_mask[base + 2 * p];
        int   m1 = rec_mask[base + 2 * p + 1];
        unsigned int lo = m0 ? (unsigned int)f2bf(w0) : 0u;
        unsigned int hi = m1 ? (unsigned int)f2bf(w1) : 0u;
        words[p] = lo | (hi << 16);
    }
    uint4 o; o.x = words[0]; o.y = words[1]; o.z = words[2]; o.w = words[3];
    Wp[(k8 << 9) | n] = o;
}

// ---------------------------------------------------------------------------
// Scan, round-11: W LDS-RESIDENT, 4-way column split, flag-synced r exchange.
//
// Rounds 6/10 proved register-prefetching the W stream collapses L2 residency
// (FETCH 67 MB -> 20 GB). And any per-step W-stream is floored by the ~150
// GB/s CU<->L2 port at ~3.4 us/step. So: 256 blocks = 64 b x 4 slices; each
// block keeps its 128x512 bf16 W-slice (128 KB) in LDS FOREVER. Per step the
// 4 sibling blocks of a batch row exchange 128-float r-slices through L2
// with seq-numbered release/acquire flags.
//
// Deadlock safety: 132 KB LDS/block forces exactly 1 block/CU; grid = 256 =
// CU count => all blocks co-resident by construction. Flag values are t+1
// (1..1024), distinct from the 0xAA workspace poison; slot parity + the
// publish(m) > spin(m-1) >= sib.publish(m-1) > sib.read(m-2) chain proves
// the 2-slot rotation is race-free. bid = s*64+b keeps siblings on one XCD
// under round-robin dispatch (performance only, not correctness).
// ---------------------------------------------------------------------------
__global__ __launch_bounds__(512, 1)
void rnn_scan_kernel(const float* __restrict__ inputs,
                     const float* __restrict__ bias,
                     const float* __restrict__ init_x,
                     const uint4* __restrict__ Wp,
                     float* __restrict__ exch,
                     int* __restrict__ flags,
                     float* __restrict__ out) {
    const int bid = blockIdx.x;
    const int s   = bid >> 6;        // slice 0..3 (siblings share XCD if rr)
    const int b   = bid & 63;        // batch row
    const int tid = threadIdx.x;
    const int q   = tid >> 7;        // k-quarter 0..3 (wave-uniform)
    const int c   = tid & 127;       // column within slice
    const int col = s * COLS + c;    // global column

    extern __shared__ char smem[];
    uint4* wlds = (uint4*)smem;                       // [64][128] = 128 KB
    float* rbuf = (float*)(smem + 64 * 128 * 16);     // [512]
    float* psum = rbuf + NDIM;                        // [QK][COLS]

    // One-time: W slice into LDS (coalesced 2 KB rows)
    for (int i = tid; i < 64 * COLS; i += 512) {
        const int k8 = i >> 7, cc = i & 127;
        wlds[k8 * COLS + cc] = Wp[(k8 << 9) + s * COLS + cc];
    }
    // r for step 0 derives from the global init state: no exchange needed.
    rbuf[tid] = tanhf(init_x[tid]);

    float x = 0.f, bias_c = 0.f, u_pref = 0.f;
    if (q == 0) {
        x      = init_x[col];
        bias_c = bias[col];
        out[(size_t)b * NDIM + col] = x;                    // t=0 output row
        u_pref = inputs[(size_t)b * NDIM + col];            // u for t=0
    }
    __syncthreads();

    for (int t = 0; t < T_STEPS; ++t) {
        // ---- MAC over this thread's k-quarter, W from LDS, r from LDS ----
        float a0 = 0.f, a1 = 0.f, a2 = 0.f, a3 = 0.f;
        const int k8base = q * 16;
#pragma unroll
        for (int k8 = 0; k8 < 16; ++k8) {
            const uint4 w = wlds[(k8base + k8) * COLS + c];
            const float4* rp = (const float4*)&rbuf[(k8base + k8) * 8];
            const float4 ra = rp[0], rb = rp[1];
            a0 = fmaf(bflo(w.x), ra.x, a0);
            a1 = fmaf(bfhi(w.x), ra.y, a1);
            a2 = fmaf(bflo(w.y), ra.z, a2);
            a3 = fmaf(bfhi(w.y), ra.w, a3);
            a0 = fmaf(bflo(w.z), rb.x, a0);
            a1 = fmaf(bfhi(w.z), rb.y, a1);
            a2 = fmaf(bflo(w.w), rb.z, a2);
            a3 = fmaf(bfhi(w.w), rb.w, a3);
        }
        psum[q * COLS + c] = (a0 + a1) + (a2 + a3);
        __syncthreads();                                    // B1: psum ready

        // ---- reduce + state update (q==0 threads own the columns) ----
        float r_new = 0.f;
        if (q == 0) {
            const float y = psum[c] + psum[COLS + c] +
                            psum[2 * COLS + c] + psum[3 * COLS + c];
            const float u = u_pref;
            const int tn = (t + 1 < T_STEPS) ? t + 1 : t;   // prefetch next u
            u_pref = inputs[(size_t)tn * BN + (size_t)b * NDIM + col];
            x = fmaf(ALPHA, (y + u + bias_c) - x, x);
            out[(size_t)(t + 1) * BN + (size_t)b * NDIM + col] = x;
            r_new = tanhf(x);
            rbuf[col] = r_new;          // own slice for next step (safe: all
                                        // step-t rbuf reads were before B1)
        }

        if (t + 1 < T_STEPS) {
            const int par = (t + 1) & 1;
            // publish own r-slice (agent-scope stores bypass stale L1 issues)
            if (q == 0) {
                __hip_atomic_store(
                    &exch[((b * NSLICE + s) * 2 + par) * COLS + c], r_new,
                    __ATOMIC_RELAXED, __HIP_MEMORY_SCOPE_AGENT);
            }
            __threadfence();
            __syncthreads();                                // B2: slice written
            if (tid == 0) {
                __hip_atomic_store(
                    &flags[((b * NSLICE + s) * 2 + par) * 32], t + 1,
                    __ATOMIC_RELEASE, __HIP_MEMORY_SCOPE_AGENT);
            }
            // spin for the 3 siblings (threads 0..2, one flag each)
            if (tid < NSLICE - 1) {
                const int os = tid + (tid >= s ? 1 : 0);
                const int* fp = &flags[((b * NSLICE + os) * 2 + par) * 32];
                while (__hip_atomic_load(fp, __ATOMIC_ACQUIRE,
                                         __HIP_MEMORY_SCOPE_AGENT) != t + 1) {
                    __builtin_amdgcn_s_sleep(4);
                }
            }
            __syncthreads();                                // B3: flags seen
            // gather 3 sibling slices into rbuf
            if (tid < (NSLICE - 1) * COLS) {
                const int j  = tid >> 7;                    // 0..2
                const int cc = tid & 127;
                const int os = j + (j >= s ? 1 : 0);
                rbuf[os * COLS + cc] = __hip_atomic_load(
                    &exch[((b * NSLICE + os) * 2 + par) * COLS + cc],
                    __ATOMIC_RELAXED, __HIP_MEMORY_SCOPE_AGENT);
            }
            __syncthreads();                                // B4: rbuf ready
        }
    }
}

// ---------------------------------------------------------------------------
// Launch
// ---------------------------------------------------------------------------
extern "C" void kernel_launch(void* const* d_in, const int* in_sizes, int n_in,
                              void* d_out, int out_size, void* d_ws, size_t ws_size,
                              hipStream_t stream) {
    const float* inputs   = (const float*)d_in[0];  // [T, B, N] fp32
    const float* W_rec    = (const float*)d_in[1];  // [N, N] fp32
    const int*   rec_mask = (const int*)d_in[2];    // [N, N] int (bool)
    const float* bias     = (const float*)d_in[3];  // [1, N] fp32
    const float* init_x   = (const float*)d_in[4];  // [N] fp32
    float*       out      = (float*)d_out;          // [T+1, B, N] fp32

    char* ws = (char*)d_ws;
    uint4* Wp    = (uint4*)ws;                      // 512 KB
    float* exch  = (float*)(ws + EXCH_OFF);         // 256 KB
    int*   flags = (int*)(ws + FLAGS_OFF);          // 64 KB

    rnn_prep_kernel<<<64, 512, 0, stream>>>(W_rec, rec_mask, Wp);

    const size_t lds_bytes = 64 * 128 * 16 + NDIM * 4 + QK * COLS * 4; // 135168
    rnn_scan_kernel<<<256, 512, lds_bytes, stream>>>(inputs, bias, init_x,
                                                     Wp, exch, flags, out);
}

// Round 14
// 2361.503 us; speedup vs baseline: 33.3026x; 15.8925x over previous
//
#include <hip/hip_runtime.h>
#include <stdint.h>

// Problem constants (match reference)
#define T_STEPS 1024
#define BATCH   64
#define NDIM    512
#define BN      (BATCH * NDIM)   // 32768
#define ALPHA   0.1f

#define NSLICE  4                // column-slices per batch row
#define COLS    128              // columns per slice
#define QK      4                // k-quarters per column

// Workspace layout
#define WP_BYTES   (64 * 512 * 16)   // 512 KB packed W
// exch64[b][s][par][w] : w in [0,64), 8B each -> 256 KB. Total ws = 768 KB.

// ---------------------------------------------------------------------------
// bf16 pack/unpack (RNE). W bf16 (absmax 0.0078 measured r5/6/10/11); this
// round sibling r-slices also travel as bf16 inside seq-tagged 64b atomics.
// ---------------------------------------------------------------------------
__device__ __forceinline__ unsigned short f2bf(float f) {
    unsigned int u = __float_as_uint(f);
    unsigned int r = (u + 0x7fffu + ((u >> 16) & 1u)) >> 16;
    return (unsigned short)r;
}
__device__ __forceinline__ float bflo(unsigned int d) { return __uint_as_float(d << 16); }
__device__ __forceinline__ float bfhi(unsigned int d) { return __uint_as_float(d & 0xffff0000u); }

// ---------------------------------------------------------------------------
// Prep: masked, transposed, bf16-packed weights.
// Wp[k8 * 512 + n] = uint4 of W_eff[n][8*k8 .. 8*k8+7] as 8 bf16.
// ---------------------------------------------------------------------------
__global__ void rnn_prep_kernel(const float* __restrict__ W_rec,
                                const int* __restrict__ rec_mask,
                                uint4* __restrict__ Wp) {
    const int k8 = blockIdx.x;
    const int n  = threadIdx.x;
    const int base = n * NDIM + k8 * 8;
    unsigned int words[4];
#pragma unroll
    for (int p = 0; p < 4; ++p) {
        float w0 = W_rec[base + 2 * p];
        float w1 = W_rec[base + 2 * p + 1];
        int   m0 = rec_mask[base + 2 * p];
        int   m1 = rec_mask[base + 2 * p + 1];
        unsigned int lo = m0 ? (unsigned int)f2bf(w0) : 0u;
        unsigned int hi = m1 ? (unsigned int)f2bf(w1) : 0u;
        words[p] = lo | (hi << 16);
    }
    uint4 o; o.x = words[0]; o.y = words[1]; o.z = words[2]; o.w = words[3];
    Wp[(k8 << 9) | n] = o;
}

// ---------------------------------------------------------------------------
// Scan, round-12 design: LDS-resident W (r11, FETCH 150 MB proven) +
// FENCELESS exchange. r11 post-mortem: 36.6 us/step, VALUBusy 2.7% -> the
// cost was __threadfence at agent scope (= L2 writeback/inv per block per
// step on a non-coherent-L2 multi-XCD chip), not the data volume.
//
// Fix: every exchanged word is a SELF-VALIDATING 64-bit relaxed agent atomic:
//   hi32 = seq (t+1, in 1..1024, != 0xAAAAAAAA poison)
//   lo32 = two bf16 r-values
// Readers spin on the word until hi32==t+1; 8B atomicity guarantees the
// payload belongs to that seq. No fence, no flag, no L2 writeback. Slot
// parity rotation is race-free: block X can only overwrite slot p with seq
// t+3 after gathering ALL seq-t+2 slices, and any sibling publishes t+2 only
// after its t+1 gather completed -> per-location order protects readers.
// Deadlock-safe: 132 KB LDS => 1 block/CU, grid=256=CU count, all resident
// (empirically held in r11). Siblings {b,64+b,128+b,192+b} = same XCD mod 8.
// ---------------------------------------------------------------------------
__global__ __launch_bounds__(512, 1)
void rnn_scan_kernel(const float* __restrict__ inputs,
                     const float* __restrict__ bias,
                     const float* __restrict__ init_x,
                     const uint4* __restrict__ Wp,
                     unsigned long long* __restrict__ exch64,
                     float* __restrict__ out) {
    const int bid = blockIdx.x;
    const int s   = bid >> 6;        // slice 0..3
    const int b   = bid & 63;        // batch row
    const int tid = threadIdx.x;
    const int q   = tid >> 7;        // k-quarter 0..3 (wave-uniform)
    const int c   = tid & 127;       // column within slice
    const int col = s * COLS + c;    // global column

    extern __shared__ char smem[];
    uint4* wlds = (uint4*)smem;                       // [64][128] = 128 KB
    float* rbuf = (float*)(smem + 64 * 128 * 16);     // [512]
    float* psum = rbuf + NDIM;                        // [QK][COLS]

    // One-time: W slice into LDS (coalesced 2 KB rows)
    for (int i = tid; i < 64 * COLS; i += 512) {
        const int k8 = i >> 7, cc = i & 127;
        wlds[k8 * COLS + cc] = Wp[(k8 << 9) + s * COLS + cc];
    }
    // Step-0 r comes from the global init state: no exchange needed.
    rbuf[tid] = tanhf(init_x[tid]);

    float x = 0.f, bias_c = 0.f, u_pref = 0.f;
    if (q == 0) {
        x      = init_x[col];
        bias_c = bias[col];
        out[(size_t)b * NDIM + col] = x;                    // t=0 output row
        u_pref = inputs[(size_t)b * NDIM + col];            // u for t=0
    }
    __syncthreads();

    for (int t = 0; t < T_STEPS; ++t) {
        // ---- MAC over this thread's k-quarter: W from LDS, r from LDS ----
        float a0 = 0.f, a1 = 0.f, a2 = 0.f, a3 = 0.f;
        const int k8base = q * 16;
#pragma unroll
        for (int k8 = 0; k8 < 16; ++k8) {
            const uint4 w = wlds[(k8base + k8) * COLS + c];
            const float4* rp = (const float4*)&rbuf[(k8base + k8) * 8];
            const float4 ra = rp[0], rb = rp[1];
            a0 = fmaf(bflo(w.x), ra.x, a0);
            a1 = fmaf(bfhi(w.x), ra.y, a1);
            a2 = fmaf(bflo(w.y), ra.z, a2);
            a3 = fmaf(bfhi(w.y), ra.w, a3);
            a0 = fmaf(bflo(w.z), rb.x, a0);
            a1 = fmaf(bfhi(w.z), rb.y, a1);
            a2 = fmaf(bflo(w.w), rb.z, a2);
            a3 = fmaf(bfhi(w.w), rb.w, a3);
        }
        psum[q * COLS + c] = (a0 + a1) + (a2 + a3);
        __syncthreads();                                    // B1: psum ready

        const int last = (t + 1 >= T_STEPS);
        const int par  = (t + 1) & 1;

        // ---- q==0: reduce, state update, publish own slice ----
        if (q == 0) {
            const float y = psum[c] + psum[COLS + c] +
                            psum[2 * COLS + c] + psum[3 * COLS + c];
            const float u = u_pref;
            const int tn = (t + 1 < T_STEPS) ? t + 1 : t;
            u_pref = inputs[(size_t)tn * BN + (size_t)b * NDIM + col];
            x = fmaf(ALPHA, (y + u + bias_c) - x, x);
            out[(size_t)(t + 1) * BN + (size_t)b * NDIM + col] = x;
            const float r_new = tanhf(x);
            rbuf[col] = r_new;              // own slice stays fp32 in LDS
            if (!last) {
                const float r_nb = __shfl_down(r_new, 1);   // pair partner
                if ((c & 1) == 0) {
                    const unsigned int payload =
                        (unsigned int)f2bf(r_new) |
                        ((unsigned int)f2bf(r_nb) << 16);
                    const unsigned long long pkt =
                        ((unsigned long long)(unsigned int)(t + 1) << 32) | payload;
                    __hip_atomic_store(
                        &exch64[(((b * NSLICE + s) * 2 + par) << 6) + (c >> 1)],
                        pkt, __ATOMIC_RELAXED, __HIP_MEMORY_SCOPE_AGENT);
                }
            }
        } else if (!last && tid >= 128 && tid < 128 + 3 * 64) {
            // ---- pollers: gather 3 sibling slices (overlaps q==0 work) ----
            const int g  = tid - 128;       // 0..191
            const int j  = g >> 6;          // 0..2
            const int w  = g & 63;          // word within slice
            const int os = j + (j >= s ? 1 : 0);
            const unsigned long long* ep =
                &exch64[(((b * NSLICE + os) * 2 + par) << 6) + w];
            unsigned long long pkt;
            for (;;) {
                pkt = __hip_atomic_load(ep, __ATOMIC_RELAXED,
                                        __HIP_MEMORY_SCOPE_AGENT);
                if ((unsigned int)(pkt >> 32) == (unsigned int)(t + 1)) break;
                __builtin_amdgcn_s_sleep(1);
            }
            const unsigned int lo = (unsigned int)pkt;
            rbuf[os * COLS + 2 * w]     = bflo(lo);   // bits[15:0]  -> f32
            rbuf[os * COLS + 2 * w + 1] = bfhi(lo);   // bits[31:16] -> f32
        }
        __syncthreads();                                    // B2: rbuf ready
    }
}

// ---------------------------------------------------------------------------
// Launch
// ---------------------------------------------------------------------------
extern "C" void kernel_launch(void* const* d_in, const int* in_sizes, int n_in,
                              void* d_out, int out_size, void* d_ws, size_t ws_size,
                              hipStream_t stream) {
    const float* inputs   = (const float*)d_in[0];  // [T, B, N] fp32
    const float* W_rec    = (const float*)d_in[1];  // [N, N] fp32
    const int*   rec_mask = (const int*)d_in[2];    // [N, N] int (bool)
    const float* bias     = (const float*)d_in[3];  // [1, N] fp32
    const float* init_x   = (const float*)d_in[4];  // [N] fp32
    float*       out      = (float*)d_out;          // [T+1, B, N] fp32

    char* ws = (char*)d_ws;
    uint4*              Wp     = (uint4*)ws;                      // 512 KB
    unsigned long long* exch64 = (unsigned long long*)(ws + WP_BYTES); // 256 KB

    rnn_prep_kernel<<<64, 512, 0, stream>>>(W_rec, rec_mask, Wp);

    const size_t lds_bytes = 64 * 128 * 16 + NDIM * 4 + QK * COLS * 4; // 135168
    rnn_scan_kernel<<<256, 512, lds_bytes, stream>>>(inputs, bias, init_x,
                                                     Wp, exch64, out);
}